// Round 2
// baseline (12954.466 us; speedup 1.0000x reference)
//
#include <hip/hip_runtime.h>
#include <hip/hip_bf16.h>

// SimpleRNN: T=1000 steps, B=64, IN=512, H=1024, O=64 (+1 value head).
// Persistent 64-block cooperative kernel: block j owns H-cols [16j,16j+16),
// eWh slice resident in VGPRs as MFMA B-fragments. Per-step device-scope
// flag barrier; out exchanged via double-buffered global f16.
// XW = x@eWx.T precomputed (131MB f16 in ws) when ws is big enough.
// Output d_out is FLOAT32 (reference returns f32) — round-1 bug was bf16 writes.

#define T_STEPS 1000
#define BATCH   64
#define INDIM   512
#define HDIM    1024
#define ODIM    64
#define ESIZE   819
#define NB      64

typedef _Float16 half8  __attribute__((ext_vector_type(8)));
typedef _Float16 half2v __attribute__((ext_vector_type(2)));
typedef float    f32x4  __attribute__((ext_vector_type(4)));

// workspace layout (bytes)
#define WS_FLAGS 0x0ull
#define WS_OUT0  0x1000ull     // 64*1024 f16 = 128KB
#define WS_OUT1  0x21000ull    // 128KB
#define WS_EWO   0x41000ull    // 64*1024 f16 = 128KB (relu+col-masked h2o)
#define WS_EWV   0x61000ull    // 1024 f16 (relu+col-masked h2v), padded to 4KB
#define WS_EWH   0x62000ull    // 1024*1024 f16 = 2MB (relu*Dale-mask h2h)
#define WS_EWX   0x262000ull   // 1024*512 f16 = 1MB (relu x2h)
#define WS_XW    0x362000ull   // 1000*64*1024 f16 = 131072000 B
#define WS_TOTAL_P1 (WS_XW + (unsigned long long)T_STEPS*BATCH*HDIM*2)

__device__ inline float dot8(half8 a, half8 b, float c) {
#if __has_builtin(__builtin_amdgcn_fdot2)
  half2v a0 = {a[0],a[1]}, a1 = {a[2],a[3]}, a2 = {a[4],a[5]}, a3 = {a[6],a[7]};
  half2v b0 = {b[0],b[1]}, b1 = {b[2],b[3]}, b2 = {b[4],b[5]}, b3 = {b[6],b[7]};
  c = __builtin_amdgcn_fdot2(a0, b0, c, false);
  c = __builtin_amdgcn_fdot2(a1, b1, c, false);
  c = __builtin_amdgcn_fdot2(a2, b2, c, false);
  c = __builtin_amdgcn_fdot2(a3, b3, c, false);
#else
  #pragma unroll
  for (int i = 0; i < 8; ++i) c += (float)a[i] * (float)b[i];
#endif
  return c;
}

// ---------------- effective weights (relu * masks), f32 -> f16 ----------------
__global__ void prep_weights(const float* __restrict__ Wh, const float* __restrict__ Wx,
                             const float* __restrict__ Wo, const float* __restrict__ Wv,
                             _Float16* __restrict__ eWh, _Float16* __restrict__ eWx,
                             _Float16* __restrict__ eWo, _Float16* __restrict__ eWv) {
  int idx = blockIdx.x * blockDim.x + threadIdx.x;
  int stride = gridDim.x * blockDim.x;
  for (int i = idx; i < HDIM*HDIM; i += stride) {
    int r = i >> 10, c = i & (HDIM-1);
    float w = fmaxf(Wh[i], 0.f);
    float s = (c < ESIZE) ? 1.f : -1.f;
    if (r == c) s = 0.f;                      // zero diagonal
    eWh[i] = (_Float16)(w * s);
  }
  for (int i = idx; i < HDIM*INDIM; i += stride)
    eWx[i] = (_Float16)fmaxf(Wx[i], 0.f);
  for (int i = idx; i < ODIM*HDIM; i += stride) {
    int k = i & (HDIM-1);
    float w = fmaxf(Wo[i], 0.f);
    eWo[i] = (_Float16)((k < ESIZE) ? w : 0.f);
  }
  for (int i = idx; i < HDIM; i += stride) {
    float w = fmaxf(Wv[i], 0.f);
    eWv[i] = (_Float16)((i < ESIZE) ? w : 0.f);
  }
}

// ---------------- phase A: XW[t,b,:] = x[t,b,:] @ eWx^T  (M=64000,N=1024,K=512)
// 250 blocks x 4 waves; each wave = one timestep (64 rows). Two passes of 2
// batch-row tiles each (A-frags 128 VGPRs resident; x re-read once, L3-hot).
// Stored in [t][jblock][b][jj] f16 layout matching rnn_seq's C-frag reads.
__global__ __launch_bounds__(256, 1) void xw_gemm(const float* __restrict__ x,
                                                  const _Float16* __restrict__ eWx,
                                                  _Float16* __restrict__ XW) {
  const int w = threadIdx.x >> 6;
  const int l = threadIdx.x & 63;
  const int t = blockIdx.x * 4 + w;
  const int m15 = l & 15, q = l >> 4;
  f32x4 z = {0.f,0.f,0.f,0.f};

  for (int half = 0; half < 2; ++half) {
    half8 af[2][16];
    #pragma unroll
    for (int mt = 0; mt < 2; ++mt) {
      const float* xr = x + ((size_t)t * BATCH + (half*2+mt)*16 + m15) * INDIM + q*8;
      #pragma unroll
      for (int kk = 0; kk < 16; ++kk) {
        f32x4 v0 = *(const f32x4*)(xr + kk*32);
        f32x4 v1 = *(const f32x4*)(xr + kk*32 + 4);
        half8 a;
        a[0]=(_Float16)v0[0]; a[1]=(_Float16)v0[1]; a[2]=(_Float16)v0[2]; a[3]=(_Float16)v0[3];
        a[4]=(_Float16)v1[0]; a[5]=(_Float16)v1[1]; a[6]=(_Float16)v1[2]; a[7]=(_Float16)v1[3];
        af[mt][kk] = a;
      }
    }
    for (int nt = 0; nt < 64; ++nt) {
      f32x4 acc[2] = {z, z};
      const _Float16* br = eWx + (size_t)(nt*16 + m15) * INDIM + q*8;
      #pragma unroll 4
      for (int kk = 0; kk < 16; ++kk) {
        half8 b = *(const half8*)(br + kk*32);
        #pragma unroll
        for (int mt = 0; mt < 2; ++mt)
          acc[mt] = __builtin_amdgcn_mfma_f32_16x16x32_f16(af[mt][kk], b, acc[mt], 0, 0, 0);
      }
      _Float16* outp = XW + (((size_t)t*64 + nt)*64)*16 + m15;
      #pragma unroll
      for (int mt = 0; mt < 2; ++mt) {
        #pragma unroll
        for (int r = 0; r < 4; ++r)
          outp[(size_t)((half*2+mt)*16 + q*4 + r)*16] = (_Float16)acc[mt][r];
      }
    }
  }
}

// ---------------- sequential recurrent kernel ----------------
template<bool USE_XW>
__global__ __launch_bounds__(256, 1) void rnn_seq(
    const float* __restrict__ x, const float* __restrict__ bh,
    const float* __restrict__ bo, const float* __restrict__ bv,
    const _Float16* __restrict__ eWh, const _Float16* __restrict__ eWx,
    const _Float16* __restrict__ eWo, const _Float16* __restrict__ eWv,
    const _Float16* __restrict__ XW,
    unsigned int* __restrict__ flags,
    _Float16* __restrict__ out0, _Float16* __restrict__ out1,
    float* __restrict__ y)
{
  const int j = blockIdx.x;            // owns H cols [16j, 16j+16)
  const int tid = threadIdx.x;
  const int w = tid >> 6;              // wave: batch rows [16w, 16w+16)
  const int l = tid & 63;
  const int m15 = l & 15, q = l >> 4;

  // eWh slice as MFMA B-fragments, resident in VGPRs for the whole run.
  // B[k][n]: n = lane&15 -> eWh row 16j+n, k = quad*8+i contiguous in that row.
  half8 wh[32];
  {
    const _Float16* base = eWh + (size_t)(j*16 + m15)*HDIM + q*8;
    #pragma unroll
    for (int kk = 0; kk < 32; ++kk) wh[kk] = *(const half8*)(base + kk*32);
  }
  half8 wx[16];
  if (!USE_XW) {
    const _Float16* base = eWx + (size_t)(j*16 + m15)*INDIM + q*8;
    #pragma unroll
    for (int kk = 0; kk < 16; ++kk) wx[kk] = *(const half8*)(base + kk*32);
  }
  const _Float16* woBase = eWo + (size_t)j*HDIM + q*8;   // readout col j weights
  const float bhv = bh[j*16 + m15];
  const float boj = bo[j];
  const float bv0 = bv[0];

  float st[4] = {0.f, 0.f, 0.f, 0.f};  // state, C-frag layout rows

  for (int t = 0; t <= T_STEPS; ++t) {
    // barrier: all blocks have published out_{t-1}  (flags[b] == t after writing out_{t-1})
    if (tid < NB) {
      while (__hip_atomic_load(&flags[tid], __ATOMIC_RELAXED, __HIP_MEMORY_SCOPE_AGENT) < (unsigned)t)
        __builtin_amdgcn_s_sleep(2);
    }
    __syncthreads();
    __threadfence();   // acquire: invalidate stale L1/L2 before reading remote out

    const _Float16* rb = (t & 1) ? out0 : out1;   // out_{t-1} = buf[(t-1)&1]
    _Float16*       wb = (t & 1) ? out1 : out0;   // out_t     = buf[t&1]

    // fused: recurrent GEMM slice (out_{t-1} @ eWh^T) + y_{t-1} col-j partials
    f32x4 acc0 = {0.f,0.f,0.f,0.f}, acc1 = {0.f,0.f,0.f,0.f};
    float p = 0.f;
    const _Float16* abase = rb + (size_t)(w*16 + m15)*HDIM + q*8;
    #pragma unroll
    for (int kk = 0; kk < 32; kk += 2) {
      half8 a0  = *(const half8*)(abase + kk*32);
      half8 a1  = *(const half8*)(abase + kk*32 + 32);
      half8 wo0 = *(const half8*)(woBase + kk*32);
      half8 wo1 = *(const half8*)(woBase + kk*32 + 32);
      acc0 = __builtin_amdgcn_mfma_f32_16x16x32_f16(a0, wh[kk],   acc0, 0, 0, 0);
      acc1 = __builtin_amdgcn_mfma_f32_16x16x32_f16(a1, wh[kk+1], acc1, 0, 0, 0);
      p = dot8(a0, wo0, p);
      p = dot8(a1, wo1, p);
    }
    // value head partial for batch row j (wave 3), from out_{t-1}
    float pv = 0.f;
    if (w == 3) {
      const half8* vo  = (const half8*)(rb + (size_t)j*HDIM + l*16);
      const half8* wv8 = (const half8*)(eWv + l*16);
      pv = dot8(vo[0], wv8[0], pv);
      pv = dot8(vo[1], wv8[1], pv);
    }

    if (t < T_STEPS) {
      if (!USE_XW) {     // fused x[t] @ eWx^T (fallback when ws too small for XW)
        const float* xr = x + ((size_t)t*BATCH + w*16 + m15)*INDIM + q*8;
        #pragma unroll
        for (int kk = 0; kk < 16; ++kk) {
          f32x4 v0 = *(const f32x4*)(xr + kk*32);
          f32x4 v1 = *(const f32x4*)(xr + kk*32 + 4);
          half8 a;
          a[0]=(_Float16)v0[0]; a[1]=(_Float16)v0[1]; a[2]=(_Float16)v0[2]; a[3]=(_Float16)v0[3];
          a[4]=(_Float16)v1[0]; a[5]=(_Float16)v1[1]; a[6]=(_Float16)v1[2]; a[7]=(_Float16)v1[3];
          acc0 = __builtin_amdgcn_mfma_f32_16x16x32_f16(a, wx[kk], acc0, 0, 0, 0);
        }
      }
      float xw[4] = {0.f,0.f,0.f,0.f};
      if (USE_XW) {
        const _Float16* xwb = XW + (((size_t)t*64 + j)*64 + w*16 + q*4)*16 + m15;
        #pragma unroll
        for (int r = 0; r < 4; ++r) xw[r] = (float)xwb[r*16];
      }
      #pragma unroll
      for (int r = 0; r < 4; ++r) {
        float tot = acc0[r] + acc1[r] + xw[r] + bhv;
        st[r] = 0.8f*st[r] + 0.2f*tot;           // (1-alpha)*state + alpha*total
        float s = fmaxf(st[r], 0.f);             // relu
        float e = __expf(2.f*s);
        float o = (s > 9.f) ? 1.f : (e - 1.f)/(e + 1.f);   // tanh(s), s>=0
        wb[(size_t)(w*16 + q*4 + r)*HDIM + j*16 + m15] = (_Float16)o;
      }
      __syncthreads();                 // waits vmcnt(0): all waves' out stores done
      if (tid == 0) {
        __threadfence();               // release: flush L2 so remote XCDs see out_t
        __hip_atomic_store(&flags[j], (unsigned)(t+1), __ATOMIC_RELAXED, __HIP_MEMORY_SCOPE_AGENT);
      }
    }

    // finish & write y_{t-1} (off the critical path, after flag release)
    if (t > 0) {
      p += __shfl_xor(p, 16);
      p += __shfl_xor(p, 32);
      if (q == 0) {
        int b = w*16 + m15;
        y[((size_t)(t-1)*BATCH + b)*(ODIM+1) + j] = p + boj;
      }
      if (w == 3) {
        pv += __shfl_xor(pv, 1);  pv += __shfl_xor(pv, 2);  pv += __shfl_xor(pv, 4);
        pv += __shfl_xor(pv, 8);  pv += __shfl_xor(pv, 16); pv += __shfl_xor(pv, 32);
        if (l == 0) y[((size_t)(t-1)*BATCH + j)*(ODIM+1) + ODIM] = pv + bv0;
      }
    }
  }
}

extern "C" void kernel_launch(void* const* d_in, const int* in_sizes, int n_in,
                              void* d_out, int out_size, void* d_ws, size_t ws_size,
                              hipStream_t stream) {
  (void)in_sizes; (void)n_in; (void)out_size;
  const float* x  = (const float*)d_in[0];
  const float* Wx = (const float*)d_in[1];
  const float* Wh = (const float*)d_in[2];
  const float* bh = (const float*)d_in[3];
  const float* Wo = (const float*)d_in[4];
  const float* bo = (const float*)d_in[5];
  const float* Wv = (const float*)d_in[6];
  const float* bv = (const float*)d_in[7];
  float* y = (float*)d_out;   // reference output dtype is float32

  char* ws = (char*)d_ws;
  unsigned int* flags = (unsigned int*)(ws + WS_FLAGS);
  _Float16* out0 = (_Float16*)(ws + WS_OUT0);
  _Float16* out1 = (_Float16*)(ws + WS_OUT1);
  _Float16* eWo  = (_Float16*)(ws + WS_EWO);
  _Float16* eWv  = (_Float16*)(ws + WS_EWV);
  _Float16* eWh  = (_Float16*)(ws + WS_EWH);
  _Float16* eWx  = (_Float16*)(ws + WS_EWX);
  _Float16* XW   = (_Float16*)(ws + WS_XW);

  // zero flags + both out buffers (ws is poisoned 0xAA before every call)
  hipMemsetAsync(ws, 0, (size_t)WS_EWO, stream);
  prep_weights<<<dim3(256), dim3(256), 0, stream>>>(Wh, Wx, Wo, Wv, eWh, eWx, eWo, eWv);

  if (ws_size >= (size_t)WS_TOTAL_P1) {
    xw_gemm<<<dim3(250), dim3(256), 0, stream>>>(x, eWx, XW);
    rnn_seq<true><<<dim3(NB), dim3(256), 0, stream>>>(
        x, bh, bo, bv, eWh, eWx, eWo, eWv, XW, flags, out0, out1, y);
  } else {
    rnn_seq<false><<<dim3(NB), dim3(256), 0, stream>>>(
        x, bh, bo, bv, eWh, eWx, eWo, eWv, XW, flags, out0, out1, y);
  }
}

// Round 3
// 11904.510 us; speedup vs baseline: 1.0882x; 1.0882x over previous
//
#include <hip/hip_runtime.h>
#include <hip/hip_bf16.h>

// SimpleRNN: T=1000 steps, B=64, IN=512, H=1024, O=64 (+1 value head).
// Persistent 64-block cooperative kernel: block j owns H-cols [16j,16j+16),
// eWh slice resident in VGPRs as MFMA B-fragments.
// R3: inter-block out exchange via agent-scope (sc1, MALL-coherent) atomic
// loads/stores — NO __threadfence (the R2 version's per-step buffer_wbl2/
// buffer_inv L2 flushes were the 12us/step bottleneck). XW re-laid-out for
// 8B/lane contiguous reads, prefetched before the flag poll; y-readout dot
// products moved after the flag release (off the serial critical path).

#define T_STEPS 1000
#define BATCH   64
#define INDIM   512
#define HDIM    1024
#define ODIM    64
#define ESIZE   819
#define NB      64

typedef _Float16 half8  __attribute__((ext_vector_type(8)));
typedef _Float16 half4  __attribute__((ext_vector_type(4)));
typedef _Float16 half2v __attribute__((ext_vector_type(2)));
typedef float    f32x4  __attribute__((ext_vector_type(4)));

// workspace layout (bytes)
#define WS_FLAGS 0x0ull
#define WS_OUT0  0x1000ull     // 64*1024 f16 = 128KB
#define WS_OUT1  0x21000ull    // 128KB
#define WS_EWO   0x41000ull    // 64*1024 f16 = 128KB (relu+col-masked h2o)
#define WS_EWV   0x61000ull    // 1024 f16 (relu+col-masked h2v), padded to 4KB
#define WS_EWH   0x62000ull    // 1024*1024 f16 = 2MB (relu*Dale-mask h2h)
#define WS_EWX   0x262000ull   // 1024*512 f16 = 1MB (relu x2h)
#define WS_XW    0x362000ull   // 1000*64*1024 f16 = 131072000 B
#define WS_TOTAL_P1 (WS_XW + (unsigned long long)T_STEPS*BATCH*HDIM*2)

// ---- coherent (agent-scope, L2-bypassing) load/store helpers ----
__device__ inline unsigned long long cload_u64(const _Float16* p) {
  return __hip_atomic_load((const unsigned long long*)p,
                           __ATOMIC_RELAXED, __HIP_MEMORY_SCOPE_AGENT);
}
__device__ inline half8 cload_b16(const _Float16* p) {
  union { unsigned long long u[2]; half8 h; } v;
  v.u[0] = cload_u64(p);
  v.u[1] = cload_u64(p + 4);
  return v.h;
}
__device__ inline void cstore_f16(_Float16* p, float x) {
  _Float16 h = (_Float16)x;
  unsigned short u = __builtin_bit_cast(unsigned short, h);
  __hip_atomic_store((unsigned short*)p, u,
                     __ATOMIC_RELAXED, __HIP_MEMORY_SCOPE_AGENT);
}

__device__ inline float dot8(half8 a, half8 b, float c) {
#if __has_builtin(__builtin_amdgcn_fdot2)
  half2v a0 = {a[0],a[1]}, a1 = {a[2],a[3]}, a2 = {a[4],a[5]}, a3 = {a[6],a[7]};
  half2v b0 = {b[0],b[1]}, b1 = {b[2],b[3]}, b2 = {b[4],b[5]}, b3 = {b[6],b[7]};
  c = __builtin_amdgcn_fdot2(a0, b0, c, false);
  c = __builtin_amdgcn_fdot2(a1, b1, c, false);
  c = __builtin_amdgcn_fdot2(a2, b2, c, false);
  c = __builtin_amdgcn_fdot2(a3, b3, c, false);
#else
  #pragma unroll
  for (int i = 0; i < 8; ++i) c += (float)a[i] * (float)b[i];
#endif
  return c;
}

// ---------------- effective weights (relu * masks), f32 -> f16 ----------------
__global__ void prep_weights(const float* __restrict__ Wh, const float* __restrict__ Wx,
                             const float* __restrict__ Wo, const float* __restrict__ Wv,
                             _Float16* __restrict__ eWh, _Float16* __restrict__ eWx,
                             _Float16* __restrict__ eWo, _Float16* __restrict__ eWv) {
  int idx = blockIdx.x * blockDim.x + threadIdx.x;
  int stride = gridDim.x * blockDim.x;
  for (int i = idx; i < HDIM*HDIM; i += stride) {
    int r = i >> 10, c = i & (HDIM-1);
    float w = fmaxf(Wh[i], 0.f);
    float s = (c < ESIZE) ? 1.f : -1.f;
    if (r == c) s = 0.f;                      // zero diagonal
    eWh[i] = (_Float16)(w * s);
  }
  for (int i = idx; i < HDIM*INDIM; i += stride)
    eWx[i] = (_Float16)fmaxf(Wx[i], 0.f);
  for (int i = idx; i < ODIM*HDIM; i += stride) {
    int k = i & (HDIM-1);
    float w = fmaxf(Wo[i], 0.f);
    eWo[i] = (_Float16)((k < ESIZE) ? w : 0.f);
  }
  for (int i = idx; i < HDIM; i += stride) {
    float w = fmaxf(Wv[i], 0.f);
    eWv[i] = (_Float16)((i < ESIZE) ? w : 0.f);
  }
}

// ---------------- phase A: XW[t,b,:] = x[t,b,:] @ eWx^T  (M=64000,N=1024,K=512)
// 250 blocks x 4 waves; each wave = one timestep (64 rows). Two passes of 2
// batch-row tiles. New layout: XW[((t*64+nt)*4 + wtile)*256 + lane*4 + r]
// so rnn_seq reads one contiguous 8B chunk per lane (coalesced, prefetchable).
__global__ __launch_bounds__(256, 1) void xw_gemm(const float* __restrict__ x,
                                                  const _Float16* __restrict__ eWx,
                                                  _Float16* __restrict__ XW) {
  const int w = threadIdx.x >> 6;
  const int l = threadIdx.x & 63;
  const int t = blockIdx.x * 4 + w;
  const int m15 = l & 15, q = l >> 4;
  f32x4 z = {0.f,0.f,0.f,0.f};

  for (int hf = 0; hf < 2; ++hf) {
    half8 af[2][16];
    #pragma unroll
    for (int mt = 0; mt < 2; ++mt) {
      const float* xr = x + ((size_t)t * BATCH + (hf*2+mt)*16 + m15) * INDIM + q*8;
      #pragma unroll
      for (int kk = 0; kk < 16; ++kk) {
        f32x4 v0 = *(const f32x4*)(xr + kk*32);
        f32x4 v1 = *(const f32x4*)(xr + kk*32 + 4);
        half8 a;
        a[0]=(_Float16)v0[0]; a[1]=(_Float16)v0[1]; a[2]=(_Float16)v0[2]; a[3]=(_Float16)v0[3];
        a[4]=(_Float16)v1[0]; a[5]=(_Float16)v1[1]; a[6]=(_Float16)v1[2]; a[7]=(_Float16)v1[3];
        af[mt][kk] = a;
      }
    }
    for (int nt = 0; nt < 64; ++nt) {
      f32x4 acc[2] = {z, z};
      const _Float16* br = eWx + (size_t)(nt*16 + m15) * INDIM + q*8;
      #pragma unroll 4
      for (int kk = 0; kk < 16; ++kk) {
        half8 b = *(const half8*)(br + kk*32);
        #pragma unroll
        for (int mt = 0; mt < 2; ++mt)
          acc[mt] = __builtin_amdgcn_mfma_f32_16x16x32_f16(af[mt][kk], b, acc[mt], 0, 0, 0);
      }
      #pragma unroll
      for (int mt = 0; mt < 2; ++mt) {
        half4 hv;
        hv[0]=(_Float16)acc[mt][0]; hv[1]=(_Float16)acc[mt][1];
        hv[2]=(_Float16)acc[mt][2]; hv[3]=(_Float16)acc[mt][3];
        *(half4*)(XW + (((size_t)t*64 + nt)*4 + (hf*2+mt))*256 + l*4) = hv;
      }
    }
  }
}

// ---------------- sequential recurrent kernel ----------------
template<bool USE_XW>
__global__ __launch_bounds__(256, 1) void rnn_seq(
    const float* __restrict__ x, const float* __restrict__ bh,
    const float* __restrict__ bo, const float* __restrict__ bv,
    const _Float16* __restrict__ eWh, const _Float16* __restrict__ eWx,
    const _Float16* __restrict__ eWo, const _Float16* __restrict__ eWv,
    const _Float16* __restrict__ XW,
    unsigned int* __restrict__ flags,
    _Float16* __restrict__ out0, _Float16* __restrict__ out1,
    float* __restrict__ y)
{
  const int j = blockIdx.x;            // owns H cols [16j, 16j+16)
  const int tid = threadIdx.x;
  const int w = tid >> 6;              // wave: batch rows [16w, 16w+16)
  const int l = tid & 63;
  const int m15 = l & 15, q = l >> 4;

  // eWh slice as MFMA B-fragments, resident in VGPRs for the whole run.
  half8 wh[32];
  {
    const _Float16* base = eWh + (size_t)(j*16 + m15)*HDIM + q*8;
    #pragma unroll
    for (int kk = 0; kk < 32; ++kk) wh[kk] = *(const half8*)(base + kk*32);
  }
  half8 wx[16];
  if (!USE_XW) {
    const _Float16* base = eWx + (size_t)(j*16 + m15)*INDIM + q*8;
    #pragma unroll
    for (int kk = 0; kk < 16; ++kk) wx[kk] = *(const half8*)(base + kk*32);
  }
  const _Float16* woBase = eWo + (size_t)j*HDIM + q*8;   // readout col j weights
  const float bhv = bh[j*16 + m15];
  const float boj = bo[j];
  const float bv0 = bv[0];

  float st[4] = {0.f, 0.f, 0.f, 0.f};  // state, C-frag layout rows

  for (int t = 0; t <= T_STEPS; ++t) {
    // prefetch XW[t] (normal cached load, independent of the barrier)
    half4 xw4 = {(_Float16)0, (_Float16)0, (_Float16)0, (_Float16)0};
    if (USE_XW && t < T_STEPS)
      xw4 = *(const half4*)(XW + (((size_t)t*64 + j)*4 + w)*256 + l*4);

    // barrier: all blocks published out_{t-1} (flags[b]==t after storing out_{t-1})
    if (tid < NB) {
      while (__hip_atomic_load(&flags[tid], __ATOMIC_RELAXED, __HIP_MEMORY_SCOPE_AGENT) < (unsigned)t)
        __builtin_amdgcn_s_sleep(1);
    }
    __syncthreads();
    // NO fence: data loads below are themselves agent-scope coherent (sc1).

    const _Float16* rb = (t & 1) ? out0 : out1;   // out_{t-1} = buf[(t-1)&1]
    _Float16*       wb = (t & 1) ? out1 : out0;   // out_t     = buf[t&1]

    // coherent gather of out_{t-1} A-fragments (all loads batched, pipelined)
    half8 a0[16], a1[16];
    const _Float16* abase = rb + (size_t)(w*16 + m15)*HDIM + q*8;
    #pragma unroll
    for (int kk = 0; kk < 16; ++kk) a0[kk] = cload_b16(abase + kk*32);
    #pragma unroll
    for (int kk = 0; kk < 16; ++kk) a1[kk] = cload_b16(abase + 512 + kk*32);
    // value-head operand: batch row j, full H (wave 3 only; wave-uniform branch)
    half8 hv0 = {}, hv1 = {};
    if (w == 3) {
      hv0 = cload_b16(rb + (size_t)j*HDIM + l*16);
      hv1 = cload_b16(rb + (size_t)j*HDIM + l*16 + 8);
    }

    f32x4 acc0 = {0.f,0.f,0.f,0.f}, acc1 = {0.f,0.f,0.f,0.f};
    #pragma unroll
    for (int kk = 0; kk < 16; ++kk) {
      acc0 = __builtin_amdgcn_mfma_f32_16x16x32_f16(a0[kk], wh[kk],    acc0, 0, 0, 0);
      acc1 = __builtin_amdgcn_mfma_f32_16x16x32_f16(a1[kk], wh[16+kk], acc1, 0, 0, 0);
    }

    if (t < T_STEPS) {
      if (!USE_XW) {     // fused x[t] @ eWx^T (fallback when ws too small for XW)
        const float* xr = x + ((size_t)t*BATCH + w*16 + m15)*INDIM + q*8;
        #pragma unroll
        for (int kk = 0; kk < 16; ++kk) {
          f32x4 v0 = *(const f32x4*)(xr + kk*32);
          f32x4 v1 = *(const f32x4*)(xr + kk*32 + 4);
          half8 a;
          a[0]=(_Float16)v0[0]; a[1]=(_Float16)v0[1]; a[2]=(_Float16)v0[2]; a[3]=(_Float16)v0[3];
          a[4]=(_Float16)v1[0]; a[5]=(_Float16)v1[1]; a[6]=(_Float16)v1[2]; a[7]=(_Float16)v1[3];
          acc0 = __builtin_amdgcn_mfma_f32_16x16x32_f16(a, wx[kk], acc0, 0, 0, 0);
        }
      }
      #pragma unroll
      for (int r = 0; r < 4; ++r) {
        float tot = acc0[r] + acc1[r] + (USE_XW ? (float)xw4[r] : 0.f) + bhv;
        st[r] = 0.8f*st[r] + 0.2f*tot;           // (1-alpha)*state + alpha*total
        float s = fmaxf(st[r], 0.f);             // relu
        float e = __expf(2.f*s);
        float o = (s > 9.f) ? 1.f : (e - 1.f)/(e + 1.f);   // tanh(s), s>=0
        cstore_f16(wb + (size_t)(w*16 + q*4 + r)*HDIM + j*16 + m15, o);
      }
      __syncthreads();   // compiler emits s_waitcnt vmcnt(0) first: coherent
                         // stores have reached the MALL before any wave passes
      if (tid == 0)
        __hip_atomic_store(&flags[j], (unsigned)(t+1),
                           __ATOMIC_RELAXED, __HIP_MEMORY_SCOPE_AGENT);
    }

    // y_{t-1} readout — off the critical path, after the flag release,
    // from the A-fragments still live in registers (no memory re-read).
    if (t > 0) {
      float p = 0.f;
      #pragma unroll
      for (int kk = 0; kk < 16; ++kk) {
        p = dot8(a0[kk], *(const half8*)(woBase + kk*32),       p);
        p = dot8(a1[kk], *(const half8*)(woBase + 512 + kk*32), p);
      }
      p += __shfl_xor(p, 16);
      p += __shfl_xor(p, 32);
      if (q == 0)
        y[((size_t)(t-1)*BATCH + w*16 + m15)*(ODIM+1) + j] = p + boj;
      if (w == 3) {
        float pv = dot8(hv0, ((const half8*)eWv)[2*l],     0.f);
        pv       = dot8(hv1, ((const half8*)eWv)[2*l + 1], pv);
        pv += __shfl_xor(pv, 1);  pv += __shfl_xor(pv, 2);  pv += __shfl_xor(pv, 4);
        pv += __shfl_xor(pv, 8);  pv += __shfl_xor(pv, 16); pv += __shfl_xor(pv, 32);
        if (l == 0) y[((size_t)(t-1)*BATCH + j)*(ODIM+1) + ODIM] = pv + bv0;
      }
    }
  }
}

extern "C" void kernel_launch(void* const* d_in, const int* in_sizes, int n_in,
                              void* d_out, int out_size, void* d_ws, size_t ws_size,
                              hipStream_t stream) {
  (void)in_sizes; (void)n_in; (void)out_size;
  const float* x  = (const float*)d_in[0];
  const float* Wx = (const float*)d_in[1];
  const float* Wh = (const float*)d_in[2];
  const float* bh = (const float*)d_in[3];
  const float* Wo = (const float*)d_in[4];
  const float* bo = (const float*)d_in[5];
  const float* Wv = (const float*)d_in[6];
  const float* bv = (const float*)d_in[7];
  float* y = (float*)d_out;   // reference output dtype is float32

  char* ws = (char*)d_ws;
  unsigned int* flags = (unsigned int*)(ws + WS_FLAGS);
  _Float16* out0 = (_Float16*)(ws + WS_OUT0);
  _Float16* out1 = (_Float16*)(ws + WS_OUT1);
  _Float16* eWo  = (_Float16*)(ws + WS_EWO);
  _Float16* eWv  = (_Float16*)(ws + WS_EWV);
  _Float16* eWh  = (_Float16*)(ws + WS_EWH);
  _Float16* eWx  = (_Float16*)(ws + WS_EWX);
  _Float16* XW   = (_Float16*)(ws + WS_XW);

  // zero flags + both out buffers (ws is poisoned 0xAA before every call)
  hipMemsetAsync(ws, 0, (size_t)WS_EWO, stream);
  prep_weights<<<dim3(256), dim3(256), 0, stream>>>(Wh, Wx, Wo, Wv, eWh, eWx, eWo, eWv);

  if (ws_size >= (size_t)WS_TOTAL_P1) {
    xw_gemm<<<dim3(250), dim3(256), 0, stream>>>(x, eWx, XW);
    rnn_seq<true><<<dim3(NB), dim3(256), 0, stream>>>(
        x, bh, bo, bv, eWh, eWx, eWo, eWv, XW, flags, out0, out1, y);
  } else {
    rnn_seq<false><<<dim3(NB), dim3(256), 0, stream>>>(
        x, bh, bo, bv, eWh, eWx, eWo, eWv, XW, flags, out0, out1, y);
  }
}

// Round 4
// 6721.789 us; speedup vs baseline: 1.9272x; 1.7710x over previous
//
#include <hip/hip_runtime.h>
#include <hip/hip_bf16.h>

// SimpleRNN: T=1000, B=64, IN=512, H=1024, O=64(+1 value).
// R4: single-XCD cooperative recurrence. 256 blocks launched; a MALL election
// picks 32 blocks on one XCD (HW_REG_XCC_ID + per-XCD counters; pigeonhole
// guarantees a winner, all 256 blocks resident => no deadlock). Participant j
// owns H-cols [32j,32j+32): eWh B-frags in VGPRs (wh0/wh1, ~256 regs ->
// 1 wave/SIMD). Cross-block exchange via the XCD's own L2: normal write-
// through stores + buffer_inv sc0 (L1 invalidate) before reads. No MALL/sc1
// ops in the hot loop (R3 showed those hops cost ~10.9us/step).
// y/value readout done as a 3rd MFMA tile (B = [eWo_2j, eWo_2j+1, eWv, 0..]
// staged in LDS) instead of serial v_dot2 chains.

#define T_STEPS 1000
#define BATCH   64
#define INDIM   512
#define HDIM    1024
#define ODIM    64
#define ESIZE   819
#define NPART   32

typedef _Float16 half8  __attribute__((ext_vector_type(8)));
typedef _Float16 half4  __attribute__((ext_vector_type(4)));
typedef _Float16 half2v __attribute__((ext_vector_type(2)));
typedef float    f32x4  __attribute__((ext_vector_type(4)));

// workspace layout (bytes)
#define WS_FLAGS 0x0ull        // NPART u32 step flags
#define WS_CNT   0x100ull      // 64 u32 per-XCD sign-in counters
#define WS_WIN   0x300ull      // u32 winner (0=unset, else xcd+1)
#define WS_OUT0  0x1000ull     // 64*1024 f16 = 128KB
#define WS_OUT1  0x21000ull
#define WS_EWO   0x41000ull    // 64*1024 f16
#define WS_EWV   0x61000ull    // 1024 f16
#define WS_EWH   0x62000ull    // 1024*1024 f16 = 2MB
#define WS_EWX   0x262000ull   // 1024*512 f16 = 1MB
#define WS_XW    0x362000ull   // 1000*64*1024 f16 = 131MB
#define WS_TOTAL_P1 (WS_XW + (unsigned long long)T_STEPS*BATCH*HDIM*2)

__device__ __forceinline__ void inv_l1_relaxed() {
  asm volatile("buffer_inv sc0" ::: "memory");
}
__device__ __forceinline__ void inv_l1_acq() {
  asm volatile("buffer_inv sc0\n\ts_waitcnt vmcnt(0)" ::: "memory");
}

// ---- helpers for the (rarely used) small-ws fallback path ----
__device__ inline unsigned long long cload_u64(const _Float16* p) {
  return __hip_atomic_load((const unsigned long long*)p,
                           __ATOMIC_RELAXED, __HIP_MEMORY_SCOPE_AGENT);
}
__device__ inline half8 cload_b16(const _Float16* p) {
  union { unsigned long long u[2]; half8 h; } v;
  v.u[0] = cload_u64(p);
  v.u[1] = cload_u64(p + 4);
  return v.h;
}
__device__ inline void cstore_f16(_Float16* p, float x) {
  _Float16 h = (_Float16)x;
  unsigned short u = __builtin_bit_cast(unsigned short, h);
  __hip_atomic_store((unsigned short*)p, u,
                     __ATOMIC_RELAXED, __HIP_MEMORY_SCOPE_AGENT);
}
__device__ inline float dot8(half8 a, half8 b, float c) {
  half2v a0 = {a[0],a[1]}, a1 = {a[2],a[3]}, a2 = {a[4],a[5]}, a3 = {a[6],a[7]};
  half2v b0 = {b[0],b[1]}, b1 = {b[2],b[3]}, b2 = {b[4],b[5]}, b3 = {b[6],b[7]};
  c = __builtin_amdgcn_fdot2(a0, b0, c, false);
  c = __builtin_amdgcn_fdot2(a1, b1, c, false);
  c = __builtin_amdgcn_fdot2(a2, b2, c, false);
  c = __builtin_amdgcn_fdot2(a3, b3, c, false);
  return c;
}

// ---------------- effective weights (relu * masks), f32 -> f16 ----------------
__global__ void prep_weights(const float* __restrict__ Wh, const float* __restrict__ Wx,
                             const float* __restrict__ Wo, const float* __restrict__ Wv,
                             _Float16* __restrict__ eWh, _Float16* __restrict__ eWx,
                             _Float16* __restrict__ eWo, _Float16* __restrict__ eWv) {
  int idx = blockIdx.x * blockDim.x + threadIdx.x;
  int stride = gridDim.x * blockDim.x;
  for (int i = idx; i < HDIM*HDIM; i += stride) {
    int r = i >> 10, c = i & (HDIM-1);
    float w = fmaxf(Wh[i], 0.f);
    float s = (c < ESIZE) ? 1.f : -1.f;
    if (r == c) s = 0.f;
    eWh[i] = (_Float16)(w * s);
  }
  for (int i = idx; i < HDIM*INDIM; i += stride)
    eWx[i] = (_Float16)fmaxf(Wx[i], 0.f);
  for (int i = idx; i < ODIM*HDIM; i += stride) {
    int k = i & (HDIM-1);
    float w = fmaxf(Wo[i], 0.f);
    eWo[i] = (_Float16)((k < ESIZE) ? w : 0.f);
  }
  for (int i = idx; i < HDIM; i += stride) {
    float w = fmaxf(Wv[i], 0.f);
    eWv[i] = (_Float16)((i < ESIZE) ? w : 0.f);
  }
}

// ---------------- phase A: XW = x @ eWx^T, layout [(t*64+nt)*4+w]*256 + l*4 ----
__global__ __launch_bounds__(256, 1) void xw_gemm(const float* __restrict__ x,
                                                  const _Float16* __restrict__ eWx,
                                                  _Float16* __restrict__ XW) {
  const int w = threadIdx.x >> 6;
  const int l = threadIdx.x & 63;
  const int t = blockIdx.x * 4 + w;
  const int m15 = l & 15, q = l >> 4;
  f32x4 z = {0.f,0.f,0.f,0.f};

  for (int hf = 0; hf < 2; ++hf) {
    half8 af[2][16];
    #pragma unroll
    for (int mt = 0; mt < 2; ++mt) {
      const float* xr = x + ((size_t)t * BATCH + (hf*2+mt)*16 + m15) * INDIM + q*8;
      #pragma unroll
      for (int kk = 0; kk < 16; ++kk) {
        f32x4 v0 = *(const f32x4*)(xr + kk*32);
        f32x4 v1 = *(const f32x4*)(xr + kk*32 + 4);
        half8 a;
        a[0]=(_Float16)v0[0]; a[1]=(_Float16)v0[1]; a[2]=(_Float16)v0[2]; a[3]=(_Float16)v0[3];
        a[4]=(_Float16)v1[0]; a[5]=(_Float16)v1[1]; a[6]=(_Float16)v1[2]; a[7]=(_Float16)v1[3];
        af[mt][kk] = a;
      }
    }
    for (int nt = 0; nt < 64; ++nt) {
      f32x4 acc[2] = {z, z};
      const _Float16* br = eWx + (size_t)(nt*16 + m15) * INDIM + q*8;
      #pragma unroll 4
      for (int kk = 0; kk < 16; ++kk) {
        half8 b = *(const half8*)(br + kk*32);
        #pragma unroll
        for (int mt = 0; mt < 2; ++mt)
          acc[mt] = __builtin_amdgcn_mfma_f32_16x16x32_f16(af[mt][kk], b, acc[mt], 0, 0, 0);
      }
      #pragma unroll
      for (int mt = 0; mt < 2; ++mt) {
        half4 hv;
        hv[0]=(_Float16)acc[mt][0]; hv[1]=(_Float16)acc[mt][1];
        hv[2]=(_Float16)acc[mt][2]; hv[3]=(_Float16)acc[mt][3];
        *(half4*)(XW + (((size_t)t*64 + nt)*4 + (hf*2+mt))*256 + l*4) = hv;
      }
    }
  }
}

// ---------------- single-XCD sequential recurrent kernel ----------------
__global__ __launch_bounds__(256, 1) void rnn_xcd(
    const float* __restrict__ bh, const float* __restrict__ bo,
    const float* __restrict__ bv,
    const _Float16* __restrict__ eWh, const _Float16* __restrict__ eWo,
    const _Float16* __restrict__ eWv, const _Float16* __restrict__ XW,
    unsigned int* __restrict__ flags, unsigned int* __restrict__ cnt,
    unsigned int* __restrict__ winner,
    _Float16* __restrict__ out0, _Float16* __restrict__ out1,
    float* __restrict__ y)
{
  const int tid = threadIdx.x;
  __shared__ int s_role;
  __shared__ half8 s_bext[32*64];   // 32KB: extra-B frags [eWo_2j, eWo_2j+1, eWv, 0..]

  // ---- election: first XCD to sign in NPART resident blocks wins ----
  if (tid == 0) {
    int xcd;
    asm volatile("s_getreg_b32 %0, hwreg(HW_REG_XCC_ID)" : "=s"(xcd));
    xcd &= 63;
    unsigned r = __hip_atomic_fetch_add(&cnt[xcd], 1u,
                    __ATOMIC_RELAXED, __HIP_MEMORY_SCOPE_AGENT);
    if (r == NPART - 1) {
      unsigned exp = 0u;
      __hip_atomic_compare_exchange_strong(winner, &exp, (unsigned)(xcd + 1),
          __ATOMIC_RELAXED, __ATOMIC_RELAXED, __HIP_MEMORY_SCOPE_AGENT);
    }
    unsigned wv;
    while ((wv = __hip_atomic_load(winner, __ATOMIC_RELAXED,
                                   __HIP_MEMORY_SCOPE_AGENT)) == 0u)
      __builtin_amdgcn_s_sleep(8);
    s_role = (xcd == (int)wv - 1 && r < NPART) ? (int)r : -1;
  }
  __syncthreads();
  const int j = s_role;           // participant rank = owned col-block pair
  if (j < 0) return;

  const int w = tid >> 6, l = tid & 63;
  const int m15 = l & 15, q = l >> 4;

  // build extra-B frags in LDS: W_ext[0]=eWo[2j], [1]=eWo[2j+1], [2]=eWv, rest 0
  if (w < 2) {
    const _Float16* src = (m15 == 0) ? eWo + (size_t)(2*j)*HDIM
                        : (m15 == 1) ? eWo + (size_t)(2*j+1)*HDIM
                        : (m15 == 2) ? eWv : (const _Float16*)0;
    for (int kk = w*16; kk < w*16 + 16; ++kk) {
      half8 v = {};
      if (src) v = *(const half8*)(src + kk*32 + q*8);
      s_bext[kk*64 + l] = v;
    }
  }

  // eWh B-frags for col-blocks 2j (cols 32j..+16) and 2j+1 (cols 32j+16..+32)
  half8 wh0[32], wh1[32];
  {
    const _Float16* b0 = eWh + (size_t)(32*j + m15)*HDIM + q*8;
    const _Float16* b1 = eWh + (size_t)(32*j + 16 + m15)*HDIM + q*8;
    #pragma unroll
    for (int kk = 0; kk < 32; ++kk) wh0[kk] = *(const half8*)(b0 + kk*32);
    #pragma unroll
    for (int kk = 0; kk < 32; ++kk) wh1[kk] = *(const half8*)(b1 + kk*32);
  }
  const float bh0 = bh[32*j + m15];
  const float bh1 = bh[32*j + 16 + m15];
  const float bxt = (m15 == 0) ? bo[2*j] : (m15 == 1) ? bo[2*j+1]
                  : (m15 == 2) ? bv[0] : 0.f;
  __syncthreads();   // s_bext ready

  float st0[4] = {0,0,0,0}, st1[4] = {0,0,0,0};

  for (int t = 0; t <= T_STEPS; ++t) {
    // ---- barrier: all ranks published out_{t-1} (flags[r]==t) ----
    if (tid < NPART) {
      for (;;) {
        inv_l1_relaxed();
        if (((volatile unsigned*)flags)[tid] >= (unsigned)t) break;
      }
    }
    __syncthreads();
    inv_l1_acq();     // L1 invalidate + drain: subsequent loads see XCD L2

    const _Float16* rb = (t & 1) ? out0 : out1;   // out_{t-1}
    _Float16*       wb = (t & 1) ? out1 : out0;   // out_t

    // XW prefetch (L2/HBM cached; consumed after the MFMA block)
    half4 xw0 = {}, xw1 = {};
    if (t < T_STEPS) {
      xw0 = *(const half4*)(XW + (((size_t)t*64 + 2*j  )*4 + w)*256 + l*4);
      xw1 = *(const half4*)(XW + (((size_t)t*64 + 2*j+1)*4 + w)*256 + l*4);
    }

    // gather A (rows 16w..+16, full K) from XCD L2 + 3-tile MFMA
    const _Float16* abase = rb + (size_t)(w*16 + m15)*HDIM + q*8;
    f32x4 acc0 = {0,0,0,0}, acc1 = {0,0,0,0}, accE = {0,0,0,0};
    #pragma unroll
    for (int hf = 0; hf < 2; ++hf) {
      half8 a[16], be[16];
      #pragma unroll
      for (int kk = 0; kk < 16; ++kk)
        a[kk] = *(const half8*)(abase + (hf*16 + kk)*32);
      #pragma unroll
      for (int kk = 0; kk < 16; ++kk)
        be[kk] = s_bext[(hf*16 + kk)*64 + l];
      #pragma unroll
      for (int kk = 0; kk < 16; ++kk) {
        acc0 = __builtin_amdgcn_mfma_f32_16x16x32_f16(a[kk], wh0[hf*16+kk], acc0, 0, 0, 0);
        acc1 = __builtin_amdgcn_mfma_f32_16x16x32_f16(a[kk], wh1[hf*16+kk], acc1, 0, 0, 0);
        accE = __builtin_amdgcn_mfma_f32_16x16x32_f16(a[kk], be[kk],        accE, 0, 0, 0);
      }
    }

    if (t < T_STEPS) {
      #pragma unroll
      for (int r = 0; r < 4; ++r) {
        float t0 = acc0[r] + (float)xw0[r] + bh0;
        float t1 = acc1[r] + (float)xw1[r] + bh1;
        st0[r] = 0.8f*st0[r] + 0.2f*t0;
        st1[r] = 0.8f*st1[r] + 0.2f*t1;
        float s0 = fmaxf(st0[r], 0.f), s1 = fmaxf(st1[r], 0.f);
        float e0 = __expf(2.f*s0),     e1 = __expf(2.f*s1);
        float o0 = (s0 > 9.f) ? 1.f : (e0 - 1.f)/(e0 + 1.f);
        float o1 = (s1 > 9.f) ? 1.f : (e1 - 1.f)/(e1 + 1.f);
        size_t row = (size_t)(w*16 + q*4 + r)*HDIM;
        wb[row + 32*j + m15]      = (_Float16)o0;   // write-through -> XCD L2
        wb[row + 32*j + 16 + m15] = (_Float16)o1;
      }
      __syncthreads();               // vmcnt(0) drain: out_t visible in L2
      if (tid == 0)
        ((volatile unsigned*)flags)[j] = (unsigned)(t + 1);
    }

    // ---- y_{t-1} from accE (extra MFMA tile), off the critical path ----
    if (t > 0 && m15 < 3 && (m15 < 2 || j == 0)) {
      int col = (m15 < 2) ? (2*j + m15) : ODIM;
      #pragma unroll
      for (int r = 0; r < 4; ++r)
        y[((size_t)(t-1)*BATCH + w*16 + q*4 + r)*(ODIM+1) + col] = accE[r] + bxt;
    }
  }
}

// ---------------- fallback (small ws): R3 kernel, fused x-GEMM ----------------
__global__ __launch_bounds__(256, 1) void rnn_small(
    const float* __restrict__ x, const float* __restrict__ bh,
    const float* __restrict__ bo, const float* __restrict__ bv,
    const _Float16* __restrict__ eWh, const _Float16* __restrict__ eWx,
    const _Float16* __restrict__ eWo, const _Float16* __restrict__ eWv,
    unsigned int* __restrict__ flags,
    _Float16* __restrict__ out0, _Float16* __restrict__ out1,
    float* __restrict__ y)
{
  const int j = blockIdx.x;
  const int tid = threadIdx.x;
  const int w = tid >> 6, l = tid & 63;
  const int m15 = l & 15, q = l >> 4;

  half8 wh[32];
  {
    const _Float16* base = eWh + (size_t)(j*16 + m15)*HDIM + q*8;
    #pragma unroll
    for (int kk = 0; kk < 32; ++kk) wh[kk] = *(const half8*)(base + kk*32);
  }
  half8 wx[16];
  {
    const _Float16* base = eWx + (size_t)(j*16 + m15)*INDIM + q*8;
    #pragma unroll
    for (int kk = 0; kk < 16; ++kk) wx[kk] = *(const half8*)(base + kk*32);
  }
  const _Float16* woBase = eWo + (size_t)j*HDIM + q*8;
  const float bhv = bh[j*16 + m15];
  const float boj = bo[j];
  const float bv0 = bv[0];
  float st[4] = {0.f, 0.f, 0.f, 0.f};

  for (int t = 0; t <= T_STEPS; ++t) {
    if (tid < 64) {
      while (__hip_atomic_load(&flags[tid], __ATOMIC_RELAXED,
                               __HIP_MEMORY_SCOPE_AGENT) < (unsigned)t)
        __builtin_amdgcn_s_sleep(1);
    }
    __syncthreads();

    const _Float16* rb = (t & 1) ? out0 : out1;
    _Float16*       wb = (t & 1) ? out1 : out0;

    half8 a0[16], a1[16];
    const _Float16* abase = rb + (size_t)(w*16 + m15)*HDIM + q*8;
    #pragma unroll
    for (int kk = 0; kk < 16; ++kk) a0[kk] = cload_b16(abase + kk*32);
    #pragma unroll
    for (int kk = 0; kk < 16; ++kk) a1[kk] = cload_b16(abase + 512 + kk*32);
    half8 hv0 = {}, hv1 = {};
    if (w == 3) {
      hv0 = cload_b16(rb + (size_t)j*HDIM + l*16);
      hv1 = cload_b16(rb + (size_t)j*HDIM + l*16 + 8);
    }

    f32x4 acc0 = {0,0,0,0}, acc1 = {0,0,0,0};
    #pragma unroll
    for (int kk = 0; kk < 16; ++kk) {
      acc0 = __builtin_amdgcn_mfma_f32_16x16x32_f16(a0[kk], wh[kk],    acc0, 0, 0, 0);
      acc1 = __builtin_amdgcn_mfma_f32_16x16x32_f16(a1[kk], wh[16+kk], acc1, 0, 0, 0);
    }

    if (t < T_STEPS) {
      const float* xr = x + ((size_t)t*BATCH + w*16 + m15)*INDIM + q*8;
      #pragma unroll
      for (int kk = 0; kk < 16; ++kk) {
        f32x4 v0 = *(const f32x4*)(xr + kk*32);
        f32x4 v1 = *(const f32x4*)(xr + kk*32 + 4);
        half8 a;
        a[0]=(_Float16)v0[0]; a[1]=(_Float16)v0[1]; a[2]=(_Float16)v0[2]; a[3]=(_Float16)v0[3];
        a[4]=(_Float16)v1[0]; a[5]=(_Float16)v1[1]; a[6]=(_Float16)v1[2]; a[7]=(_Float16)v1[3];
        acc0 = __builtin_amdgcn_mfma_f32_16x16x32_f16(a, wx[kk], acc0, 0, 0, 0);
      }
      #pragma unroll
      for (int r = 0; r < 4; ++r) {
        float tot = acc0[r] + acc1[r] + bhv;
        st[r] = 0.8f*st[r] + 0.2f*tot;
        float s = fmaxf(st[r], 0.f);
        float e = __expf(2.f*s);
        float o = (s > 9.f) ? 1.f : (e - 1.f)/(e + 1.f);
        cstore_f16(wb + (size_t)(w*16 + q*4 + r)*HDIM + j*16 + m15, o);
      }
      __syncthreads();
      if (tid == 0)
        __hip_atomic_store(&flags[j], (unsigned)(t+1),
                           __ATOMIC_RELAXED, __HIP_MEMORY_SCOPE_AGENT);
    }

    if (t > 0) {
      float p = 0.f;
      #pragma unroll
      for (int kk = 0; kk < 16; ++kk) {
        p = dot8(a0[kk], *(const half8*)(woBase + kk*32),       p);
        p = dot8(a1[kk], *(const half8*)(woBase + 512 + kk*32), p);
      }
      p += __shfl_xor(p, 16);
      p += __shfl_xor(p, 32);
      if (q == 0)
        y[((size_t)(t-1)*BATCH + w*16 + m15)*(ODIM+1) + j] = p + boj;
      if (w == 3) {
        float pv = dot8(hv0, ((const half8*)eWv)[2*l],     0.f);
        pv       = dot8(hv1, ((const half8*)eWv)[2*l + 1], pv);
        pv += __shfl_xor(pv, 1);  pv += __shfl_xor(pv, 2);  pv += __shfl_xor(pv, 4);
        pv += __shfl_xor(pv, 8);  pv += __shfl_xor(pv, 16); pv += __shfl_xor(pv, 32);
        if (l == 0) y[((size_t)(t-1)*BATCH + j)*(ODIM+1) + ODIM] = pv + bv0;
      }
    }
  }
}

extern "C" void kernel_launch(void* const* d_in, const int* in_sizes, int n_in,
                              void* d_out, int out_size, void* d_ws, size_t ws_size,
                              hipStream_t stream) {
  (void)in_sizes; (void)n_in; (void)out_size;
  const float* x  = (const float*)d_in[0];
  const float* Wx = (const float*)d_in[1];
  const float* Wh = (const float*)d_in[2];
  const float* bh = (const float*)d_in[3];
  const float* Wo = (const float*)d_in[4];
  const float* bo = (const float*)d_in[5];
  const float* Wv = (const float*)d_in[6];
  const float* bv = (const float*)d_in[7];
  float* y = (float*)d_out;

  char* ws = (char*)d_ws;
  unsigned int* flags  = (unsigned int*)(ws + WS_FLAGS);
  unsigned int* cnt    = (unsigned int*)(ws + WS_CNT);
  unsigned int* winner = (unsigned int*)(ws + WS_WIN);
  _Float16* out0 = (_Float16*)(ws + WS_OUT0);
  _Float16* out1 = (_Float16*)(ws + WS_OUT1);
  _Float16* eWo  = (_Float16*)(ws + WS_EWO);
  _Float16* eWv  = (_Float16*)(ws + WS_EWV);
  _Float16* eWh  = (_Float16*)(ws + WS_EWH);
  _Float16* eWx  = (_Float16*)(ws + WS_EWX);
  _Float16* XW   = (_Float16*)(ws + WS_XW);

  // zero flags + election state + both out buffers
  hipMemsetAsync(ws, 0, (size_t)WS_EWO, stream);
  prep_weights<<<dim3(256), dim3(256), 0, stream>>>(Wh, Wx, Wo, Wv, eWh, eWx, eWo, eWv);

  if (ws_size >= (size_t)WS_TOTAL_P1) {
    xw_gemm<<<dim3(250), dim3(256), 0, stream>>>(x, eWx, XW);
    rnn_xcd<<<dim3(256), dim3(256), 0, stream>>>(
        bh, bo, bv, eWh, eWo, eWv, XW, flags, cnt, winner, out0, out1, y);
  } else {
    rnn_small<<<dim3(64), dim3(256), 0, stream>>>(
        x, bh, bo, bv, eWh, eWx, eWo, eWv, flags, out0, out1, y);
  }
}